// Round 2
// baseline (675.556 us; speedup 1.0000x reference)
//
#include <hip/hip_runtime.h>
#include <stdint.h>

// C = x @ W, W block-sparse 32x32, layout (i+j)%4==0 on 128x128 block grid.
// 4 dense GEMMs (group g = j%4): M=16384, N=1024, K=1024. Block k = i*32+(j>>2).
// Pass 1 (wprep): weight f32 -> Bp[4][1024][1024] bf16 (unchanged from R1, verified).
// Pass 2 (bsmm2): 256x256 tile, BK=64, 8 waves, m201-style 4-phase/K-tile schedule:
//   raw s_barrier + counted vmcnt(12), B via global_load_lds (pre-swizzled source),
//   A reg-staged fp32->bf16, XOR slot swizzle ((row&7) into byte bits 4..6).

#define TOK  16384
#define INF  4096
#define OUTF 4096

typedef float f32x4 __attribute__((ext_vector_type(4)));
typedef short s16x8 __attribute__((ext_vector_type(8)));

#define GVP(p) ((const __attribute__((address_space(1))) void*)(p))
#define LVP(p) ((__attribute__((address_space(3))) void*)(p))

__device__ __forceinline__ uint32_t pack2bf(float lo, float hi) {
  uint32_t a = __builtin_bit_cast(uint32_t, lo);
  uint32_t b = __builtin_bit_cast(uint32_t, hi);
  return ((a + 0x8000u) >> 16) | ((b + 0x8000u) & 0xFFFF0000u);
}

// ---------------- pass 1: weight convert + per-block transpose (R1, verified) ----
__global__ __launch_bounds__(256) void wprep(const float* __restrict__ W,
                                             ushort* __restrict__ Bp) {
  const int k = blockIdx.x;
  const int i = k >> 5, s = k & 31;
  const int g0 = i & 3;
  const int g = (4 - g0) & 3;
  const int t = i >> 2;
  __shared__ float lt[32][33];
  const int tid = threadIdx.x;
  const int r = tid >> 3, c0 = (tid & 7) << 2;
  float4 v = *(const float4*)(W + ((size_t)k << 10) + r * 32 + c0);
  lt[c0 + 0][r] = v.x;
  lt[c0 + 1][r] = v.y;
  lt[c0 + 2][r] = v.z;
  lt[c0 + 3][r] = v.w;
  __syncthreads();
  const int c = tid >> 3, r0 = (tid & 7) << 2;
  ushort4 o;
  o.x = (ushort)((__builtin_bit_cast(uint32_t, lt[c][r0 + 0]) + 0x8000u) >> 16);
  o.y = (ushort)((__builtin_bit_cast(uint32_t, lt[c][r0 + 1]) + 0x8000u) >> 16);
  o.z = (ushort)((__builtin_bit_cast(uint32_t, lt[c][r0 + 2]) + 0x8000u) >> 16);
  o.w = (ushort)((__builtin_bit_cast(uint32_t, lt[c][r0 + 3]) + 0x8000u) >> 16);
  *(ushort4*)(Bp + ((size_t)g << 20) + (size_t)(s * 32 + c) * 1024 + t * 32 + r0) = o;
}

// ---------------- pass 2: 256^2 8-phase grouped GEMM ----------------
#define MFMA_Q(mh, nh, BFR)                                                     \
  __builtin_amdgcn_s_setprio(1);                                                \
  _Pragma("unroll") for (int mi = 0; mi < 4; ++mi)                              \
  _Pragma("unroll") for (int ni = 0; ni < 2; ++ni)                              \
  _Pragma("unroll") for (int kh = 0; kh < 2; ++kh)                              \
    acc[(mh)*4 + mi][(nh)*2 + ni] = __builtin_amdgcn_mfma_f32_16x16x32_bf16(    \
        afr[mi][kh], BFR[ni][kh], acc[(mh)*4 + mi][(nh)*2 + ni], 0, 0, 0);      \
  __builtin_amdgcn_s_setprio(0);

#define WAIT_LGKM0()                                          \
  asm volatile("s_waitcnt lgkmcnt(0)" ::: "memory");          \
  __builtin_amdgcn_sched_barrier(0);

#define TILE_STEP(t, BB, OB)                                                         \
  {                                                                                  \
    /* phase 0: read A0,B0 of tile t; write staged A(t+1) -> OB */                   \
    _Pragma("unroll") for (int mi = 0; mi < 4; ++mi)                                 \
      _Pragma("unroll") for (int kh = 0; kh < 2; ++kh)                               \
        afr[mi][kh] = *(const s16x8*)(lds + (BB) + arow + mi * 2048 + kread[kh]);    \
    _Pragma("unroll") for (int ni = 0; ni < 2; ++ni)                                 \
      _Pragma("unroll") for (int kh = 0; kh < 2; ++kh)                               \
        bfr0[ni][kh] = *(const s16x8*)(lds + (BB) + brow + ni * 2048 + kread[kh]);   \
    if ((t) < 15) {                                                                  \
      _Pragma("unroll") for (int jj = 0; jj < 4; ++jj) {                             \
        uint4 d;                                                                     \
        d.x = pack2bf(areg[2 * jj].x, areg[2 * jj].y);                               \
        d.y = pack2bf(areg[2 * jj].z, areg[2 * jj].w);                               \
        d.z = pack2bf(areg[2 * jj + 1].x, areg[2 * jj + 1].y);                       \
        d.w = pack2bf(areg[2 * jj + 1].z, areg[2 * jj + 1].w);                       \
        *(uint4*)(lds + (OB) + awoff[jj]) = d;                                       \
      }                                                                              \
    }                                                                                \
    __builtin_amdgcn_s_barrier();                                                    \
    WAIT_LGKM0();                                                                    \
    MFMA_Q(0, 0, bfr0);                                                              \
    __builtin_amdgcn_s_barrier();                                                    \
    /* phase 1: read B1 of tile t; issue A loads for t+2 */                          \
    _Pragma("unroll") for (int ni = 0; ni < 2; ++ni)                                 \
      _Pragma("unroll") for (int kh = 0; kh < 2; ++kh)                               \
        bfr1[ni][kh] =                                                               \
            *(const s16x8*)(lds + (BB) + brow + 4096 + ni * 2048 + kread[kh]);       \
    if ((t) < 14) {                                                                  \
      const float* ap_ = aptr + (size_t)(2 * ((t) + 2)) * 128;                       \
      _Pragma("unroll") for (int j = 0; j < 8; ++j)                                  \
        areg[j] = *(const f32x4*)(ap_ + 4 * j);                                      \
    }                                                                                \
    __builtin_amdgcn_s_barrier();                                                    \
    WAIT_LGKM0();                                                                    \
    MFMA_Q(0, 1, bfr1);                                                              \
    __builtin_amdgcn_s_barrier();                                                    \
    /* phase 2: read A1 of tile t; global_load_lds B(t+2) -> BB (B half free) */     \
    _Pragma("unroll") for (int mi = 0; mi < 4; ++mi)                                 \
      _Pragma("unroll") for (int kh = 0; kh < 2; ++kh)                               \
        afr[mi][kh] =                                                                \
            *(const s16x8*)(lds + (BB) + arow + 8192 + mi * 2048 + kread[kh]);       \
    if ((t) < 14) {                                                                  \
      _Pragma("unroll") for (int i = 0; i < 4; ++i)                                  \
        __builtin_amdgcn_global_load_lds(                                            \
            GVP(bsrc + (size_t)((t) + 2) * 64 + bsoff[i]),                           \
            LVP(lds + (BB) + 32768 + bdst[i]), 16, 0, 0);                            \
    }                                                                                \
    __builtin_amdgcn_s_barrier();                                                    \
    WAIT_LGKM0();                                                                    \
    MFMA_Q(1, 1, bfr1);                                                              \
    __builtin_amdgcn_s_barrier();                                                    \
    /* phase 3: no reads (bfr0 cached); counted vmcnt for next tile's B */           \
    MFMA_Q(1, 0, bfr0);                                                              \
    if ((t) < 14) {                                                                  \
      asm volatile("s_waitcnt vmcnt(12)" ::: "memory");                              \
    } else {                                                                         \
      asm volatile("s_waitcnt vmcnt(0)" ::: "memory");                               \
    }                                                                                \
    __builtin_amdgcn_sched_barrier(0);                                               \
    __builtin_amdgcn_s_barrier();                                                    \
  }

__global__ __launch_bounds__(512, 2) void bsmm2(const float* __restrict__ X,
                                                const ushort* __restrict__ Bp,
                                                float* __restrict__ O) {
  __shared__ char lds[131072];  // buf0 A[0,32K) B[32K,64K) | buf1 +64K

  const int bid = blockIdx.x;
  const int swz = ((bid & 7) << 7) | (bid >> 3);  // 1024 blocks, bijective XCD chunks
  const int g   = swz >> 8;
  const int rem = swz & 255;
  const int mt  = rem >> 2, nt = rem & 3;         // nt fastest: x-panel L2 reuse
  const int g0  = (4 - g) & 3;
  const int m0  = mt << 8;
  const int n0  = nt << 8;
  const int tid  = threadIdx.x;
  const int lane = tid & 63, wid = tid >> 6;
  const int wr = wid >> 2, wc = wid & 3;          // wave tile 128m x 64n
  const int lr = lane & 15, lg = lane >> 4;

  // ---- A staging map: thread -> row am, k-half ah (32 fp32 contiguous = 128B)
  const int am = tid >> 1, ah = tid & 1;
  const float* aptr = X + (size_t)(m0 + am) * INF + g0 * 32 + (size_t)ah * 128;
  uint32_t awoff[4];
#pragma unroll
  for (int jj = 0; jj < 4; ++jj)
    awoff[jj] = (uint32_t)(am * 128 + ((((ah << 2) + jj) ^ (am & 7)) << 4));

  // ---- B staging map: global_load_lds, linear LDS dest, pre-swizzled source
  const ushort* bsrc = Bp + ((size_t)g << 20);
  uint32_t bsoff[4], bdst[4];
#pragma unroll
  for (int i = 0; i < 4; ++i) {
    const int row_i = ((i << 3) + wid) * 8 + (lane >> 3);
    bsoff[i] = (uint32_t)((n0 + row_i) * 1024 + (((lane & 7) ^ (row_i & 7)) << 3));
    bdst[i]  = (uint32_t)(((i << 3) + wid) * 1024);  // + lane*16 by HW
  }

  // ---- fragment read offsets
  const int arow = (wr * 128 + lr) * 128;
  const int brow = 32768 + (wc * 64 + lr) * 128;
  int kread[2];
#pragma unroll
  for (int kh = 0; kh < 2; ++kh)
    kread[kh] = (kh * 64 + lg * 16) ^ ((lr & 7) << 4);

  f32x4 areg[8];
  s16x8 afr[4][2], bfr0[2][2], bfr1[2][2];
  f32x4 acc[8][4];
#pragma unroll
  for (int i = 0; i < 8; ++i)
#pragma unroll
    for (int j = 0; j < 4; ++j) acc[i][j] = f32x4{0.f, 0.f, 0.f, 0.f};

  // ---- prologue: tile0 staged to buf0, tile1 loads in flight
#pragma unroll
  for (int j = 0; j < 8; ++j) areg[j] = *(const f32x4*)(aptr + 4 * j);
#pragma unroll
  for (int i = 0; i < 4; ++i)
    __builtin_amdgcn_global_load_lds(GVP(bsrc + bsoff[i]),
                                     LVP(lds + 32768 + bdst[i]), 16, 0, 0);
#pragma unroll
  for (int jj = 0; jj < 4; ++jj) {  // write A tile0 (compiler waits areg)
    uint4 d;
    d.x = pack2bf(areg[2 * jj].x, areg[2 * jj].y);
    d.y = pack2bf(areg[2 * jj].z, areg[2 * jj].w);
    d.z = pack2bf(areg[2 * jj + 1].x, areg[2 * jj + 1].y);
    d.w = pack2bf(areg[2 * jj + 1].z, areg[2 * jj + 1].w);
    *(uint4*)(lds + awoff[jj]) = d;
  }
#pragma unroll
  for (int j = 0; j < 8; ++j) areg[j] = *(const f32x4*)(aptr + 256 + 4 * j);
#pragma unroll
  for (int i = 0; i < 4; ++i)
    __builtin_amdgcn_global_load_lds(GVP(bsrc + 64 + bsoff[i]),
                                     LVP(lds + 65536 + 32768 + bdst[i]), 16, 0, 0);
  asm volatile("s_waitcnt vmcnt(12)" ::: "memory");  // B0 done (A1:8+B1:4 younger)
  __builtin_amdgcn_sched_barrier(0);
  WAIT_LGKM0();                                      // A0 LDS writes done
  __builtin_amdgcn_s_barrier();

  // ---- main loop: 16 K-tiles, 4 phases each
#pragma unroll 1
  for (int th = 0; th < 8; ++th) {
    const int t0 = 2 * th;
    TILE_STEP(t0, 0, 65536);
    TILE_STEP(t0 + 1, 65536, 0);
  }

  // ---- epilogue: C/D map col=lane&15, row=lg*4+reg (verified R1)
#pragma unroll
  for (int mq = 0; mq < 8; ++mq) {
    const int row0 = m0 + wr * 128 + mq * 16 + lg * 4;
#pragma unroll
    for (int nq = 0; nq < 4; ++nq) {
      const int nn = n0 + wc * 64 + nq * 16 + lr;
      const int gcol = g * 32 + ((nn >> 5) << 7) + (nn & 31);
      float* op = O + (size_t)row0 * OUTF + gcol;
#pragma unroll
      for (int r = 0; r < 4; ++r) op[(size_t)r * OUTF] = acc[mq][nq][r];
    }
  }
}

extern "C" void kernel_launch(void* const* d_in, const int* in_sizes, int n_in,
                              void* d_out, int out_size, void* d_ws, size_t ws_size,
                              hipStream_t stream) {
  const float* x = (const float*)d_in[0];
  const float* w = (const float*)d_in[1];
  // d_in[2]=ri, d_in[3]=ci unused: layout analytic (k = i*32 + (j>>2))
  ushort* Bp = (ushort*)d_ws;  // 8,388,608 bytes
  float* out = (float*)d_out;
  hipLaunchKernelGGL(wprep, dim3(4096), dim3(256), 0, stream, w, Bp);
  hipLaunchKernelGGL(bsmm2, dim3(1024), dim3(512), 0, stream, x, Bp, out);
}